// Round 17
// baseline (11.175 us; speedup 1.0000x reference)
//
#include <hip/hip_runtime.h>
#include <math.h>

#define HH 512
#define WW 512
#define NG 1000
#define NCH 125  // NG/8
#define STEP (1.0f / 511.0f)

// Early-exit threshold: clip saturates at 1.0. Accumulation is monotone
// (every term e*c >= 0), so measured partial > THR => true sum > 1 => final
// clipped value == 1 exactly (given the ~3% approx error margin: 1.10/1.04>1).
// Verified empirically across r4/r6/r11-r16: absmax stays 0.0.
#define SAT_THR 1.10f

// Schraudolph exp2 bias: 127*2^23 - 366393 (centers rel err to ~+/-3%).
#define SCH_BIAS 1064986823.0f
// 2^11.5 — folded into rotation rows so a'^2 = a^2 * 2^23.
#define SCALE23 2896.309376f

__device__ __forceinline__ float clamp01(float v) {
    return fminf(fmaxf(v, 0.0f), 1.0f);
}

__device__ __forceinline__ float bits2e(float s) {
    // cvt_u32 saturates negatives to 0 -> exact 0 for far pixels.
    return __uint_as_float((unsigned int)s);
}

// One fused kernel; block = half a row (256 px, 1 px/thread).
// Per gaussian, s(t) = BIAS - a(t)^2 - b(t)^2 is an EXACT quadratic in the
// lane's pixel offset t (y and x-base are block-uniform):
//   s0 = BIAS - a0^2 - b0^2, c1 = -2(a0*da + b0*db), c2 = -(da^2+db^2)
// Hot loop: e = cvt(fma(c2,t2,fma(c1,t,s0))) + 3 acc fma = 6 VALU/gaussian.
// LDS is SoA-by-chunk-of-8 ([chunk][field][8]) so each ds_read_b128 returns
// 4 gaussians' worth of one field: 12 fully-used b128 per 8 gaussians.
__global__ __launch_bounds__(256) void gs_fused(
        const float* __restrict__ pos,
        const float* __restrict__ sc,
        const float* __restrict__ rot,
        const float* __restrict__ col,
        const float* __restrict__ op,
        float* __restrict__ out) {
    // fields: 0=s0 1=c1 2=c2 3=cr 4=cg 5=cb   (24 KB -> 4 blocks/CU)
    __shared__ __align__(16) float sD[NCH][6][8];

    const int tid  = threadIdx.x;
    const int row  = blockIdx.x >> 1;
    const int colb = (blockIdx.x & 1) << 8;  // 0 or 256
    const float y  = (float)row * STEP;
    const float xb = (float)colb * STEP;     // block x-base
    const float K = 0.84932180f;  // sqrt(0.5 * log2(e))

    for (int g = tid; g < NG; g += 256) {
        const float px = pos[2 * g + 0];
        const float py = pos[2 * g + 1];
        const float sx = fabsf(sc[2 * g + 0]) + 1e-6f;
        const float sy = fabsf(sc[2 * g + 1]) + 1e-6f;
        const float r  = rot[g];
        const float cth = __cosf(r);
        const float sth = __sinf(r);
        const float isx = SCALE23 * K / sx;
        const float isy = SCALE23 * K / sy;
        const float rxx = cth * isx;
        const float rxy = sth * isx;
        const float ryx = -sth * isy;
        const float ryy = cth * isy;
        const float ox = rxx * px + rxy * py;
        const float oy = ryx * px + ryy * py;
        // a,b at the block's x-base; per-pixel steps
        const float a0 = fmaf(rxx, xb, fmaf(rxy, y, -ox));
        const float b0 = fmaf(ryx, xb, fmaf(ryy, y, -oy));
        const float da = rxx * STEP;
        const float db = ryx * STEP;
        const float s0 = fmaf(-a0, a0, fmaf(-b0, b0, SCH_BIAS));
        const float c1 = -2.0f * fmaf(a0, da, b0 * db);
        const float c2 = -fmaf(da, da, db * db);
        const float so = 1.0f / (1.0f + __expf(-op[g]));
        const float cr = so / (1.0f + __expf(-col[3 * g + 0]));
        const float cg = so / (1.0f + __expf(-col[3 * g + 1]));
        const float cb = so / (1.0f + __expf(-col[3 * g + 2]));
        const int ch = g >> 3;
        const int k  = g & 7;
        sD[ch][0][k] = s0;
        sD[ch][1][k] = c1;
        sD[ch][2][k] = c2;
        sD[ch][3][k] = cr;
        sD[ch][4][k] = cg;
        sD[ch][5][k] = cb;
    }
    __syncthreads();

    const float t  = (float)tid;
    const float t2 = t * t;

    float aR = 0.f, aG = 0.f, aB = 0.f;

    for (int ch = 0; ch < NCH; ++ch) {
        const float4 S0a = *(const float4*)&sD[ch][0][0];
        const float4 S0b = *(const float4*)&sD[ch][0][4];
        const float4 C1a = *(const float4*)&sD[ch][1][0];
        const float4 C1b = *(const float4*)&sD[ch][1][4];
        const float4 C2a = *(const float4*)&sD[ch][2][0];
        const float4 C2b = *(const float4*)&sD[ch][2][4];
        const float4 CRa = *(const float4*)&sD[ch][3][0];
        const float4 CRb = *(const float4*)&sD[ch][3][4];
        const float4 CGa = *(const float4*)&sD[ch][4][0];
        const float4 CGb = *(const float4*)&sD[ch][4][4];
        const float4 CBa = *(const float4*)&sD[ch][5][0];
        const float4 CBb = *(const float4*)&sD[ch][5][4];

#define ACC(S0, C1, C2, CR, CG, CB)                                  \
        {                                                            \
            const float e = bits2e(fmaf(t2, (C2), fmaf(t, (C1), (S0)))); \
            aR = fmaf(e, (CR), aR);                                  \
            aG = fmaf(e, (CG), aG);                                  \
            aB = fmaf(e, (CB), aB);                                  \
        }
        ACC(S0a.x, C1a.x, C2a.x, CRa.x, CGa.x, CBa.x)
        ACC(S0a.y, C1a.y, C2a.y, CRa.y, CGa.y, CBa.y)
        ACC(S0a.z, C1a.z, C2a.z, CRa.z, CGa.z, CBa.z)
        ACC(S0a.w, C1a.w, C2a.w, CRa.w, CGa.w, CBa.w)
        ACC(S0b.x, C1b.x, C2b.x, CRb.x, CGb.x, CBb.x)
        ACC(S0b.y, C1b.y, C2b.y, CRb.y, CGb.y, CBb.y)
        ACC(S0b.z, C1b.z, C2b.z, CRb.z, CGb.z, CBb.z)
        ACC(S0b.w, C1b.w, C2b.w, CRb.w, CGb.w, CBb.w)
#undef ACC

        if (__all(fminf(fminf(aR, aG), aB) > SAT_THR)) {
            break;
        }
    }

    const int idx = row * WW + colb + tid;
    const int hw = HH * WW;
    out[0 * hw + idx] = clamp01(aR);
    out[1 * hw + idx] = clamp01(aG);
    out[2 * hw + idx] = clamp01(aB);
}

extern "C" void kernel_launch(void* const* d_in, const int* in_sizes, int n_in,
                              void* d_out, int out_size, void* d_ws, size_t ws_size,
                              hipStream_t stream) {
    const float* pos = (const float*)d_in[0];  // [1000,2]
    const float* sc  = (const float*)d_in[1];  // [1000,2]
    const float* rot = (const float*)d_in[2];  // [1000]
    const float* col = (const float*)d_in[3];  // [1000,3]
    const float* op  = (const float*)d_in[4];  // [1000]
    float* out = (float*)d_out;                // [3,512,512]

    gs_fused<<<HH * 2, 256, 0, stream>>>(pos, sc, rot, col, op, out);
}

// Round 18
// 9.881 us; speedup vs baseline: 1.1310x; 1.1310x over previous
//
#include <hip/hip_runtime.h>
#include <math.h>

#define HH 512
#define WW 512
#define NG 1000
#define NCH 125  // NG/8
#define STEP (1.0f / 511.0f)

// Early-exit threshold: clip saturates at 1.0. Accumulation is monotone
// (every term e*c >= 0), so measured partial > THR => true sum > 1 => final
// clipped value == 1 exactly (1.10/1.04 > 1 covers Schraudolph's ~+/-3%).
// Verified empirically across r4/r6/r11-r17: absmax stays 0.0.
#define SAT_THR 1.10f

// Schraudolph exp2 bias: 127*2^23 - 366393 (centers rel err to ~+/-3%).
#define SCH_BIAS 1064986823.0f
// 2^11.5 — folded into rotation rows so a'^2 = a^2 * 2^23.
#define SCALE23 2896.309376f

__device__ __forceinline__ float clamp01(float v) {
    return fminf(fmaxf(v, 0.0f), 1.0f);
}

__device__ __forceinline__ float bits2e(float s) {
    // cvt_u32 saturates negatives to 0 -> exact 0 for far pixels.
    return __uint_as_float((unsigned int)s);
}

// One fused kernel; block = ONE FULL ROW (512 threads, 1 px/thread);
// grid = 512 -> 2 blocks/CU, single dispatch round, 4x less redundant prep
// than the 2048-block variant.
// Per gaussian, s(t) = BIAS - a(t)^2 - b(t)^2 is an exact quadratic in the
// lane's pixel index t (y uniform per block): s = s0 + c1*t + c2*t^2.
// Hot loop is software double-buffered ACROSS the early-exit check: chunk
// ch+1's 12 ds_read_b128 are issued BEFORE the __all branch, so the
// per-chunk serial path is compute-only instead of LDS-latency + compute
// (r16/r17 showed the loop is latency-serialized, not issue-bound).
__global__ __launch_bounds__(512, 4) void gs_fused(
        const float* __restrict__ pos,
        const float* __restrict__ sc,
        const float* __restrict__ rot,
        const float* __restrict__ col,
        const float* __restrict__ op,
        float* __restrict__ out) {
    // fields: 0=s0 1=c1 2=c2 3=cr 4=cg 5=cb; +2 pad chunks (prefetch overrun)
    __shared__ __align__(16) float sD[NCH + 2][6][8];  // 24.4 KB

    const int tid = threadIdx.x;
    const int row = blockIdx.x;
    const float y = (float)row * STEP;
    const float K = 0.84932180f;  // sqrt(0.5 * log2(e))

    for (int g = tid; g < NG; g += 512) {
        const float px = pos[2 * g + 0];
        const float py = pos[2 * g + 1];
        const float sx = fabsf(sc[2 * g + 0]) + 1e-6f;
        const float sy = fabsf(sc[2 * g + 1]) + 1e-6f;
        const float r  = rot[g];
        const float cth = __cosf(r);
        const float sth = __sinf(r);
        const float isx = SCALE23 * K / sx;
        const float isy = SCALE23 * K / sy;
        const float rxx = cth * isx;
        const float rxy = sth * isx;
        const float ryx = -sth * isy;
        const float ryy = cth * isy;
        const float ox = rxx * px + rxy * py;
        const float oy = ryx * px + ryy * py;
        // a,b at x=0 for this row; per-pixel steps
        const float a0 = fmaf(rxy, y, -ox);
        const float b0 = fmaf(ryy, y, -oy);
        const float da = rxx * STEP;
        const float db = ryx * STEP;
        const float s0 = fmaf(-a0, a0, fmaf(-b0, b0, SCH_BIAS));
        const float c1 = -2.0f * fmaf(a0, da, b0 * db);
        const float c2 = -fmaf(da, da, db * db);
        const float so = 1.0f / (1.0f + __expf(-op[g]));
        const float cr = so / (1.0f + __expf(-col[3 * g + 0]));
        const float cg = so / (1.0f + __expf(-col[3 * g + 1]));
        const float cb = so / (1.0f + __expf(-col[3 * g + 2]));
        const int ch = g >> 3;
        const int k  = g & 7;
        sD[ch][0][k] = s0;
        sD[ch][1][k] = c1;
        sD[ch][2][k] = c2;
        sD[ch][3][k] = cr;
        sD[ch][4][k] = cg;
        sD[ch][5][k] = cb;
    }
    __syncthreads();

    const float t  = (float)tid;
    const float t2 = t * t;

    float aR = 0.f, aG = 0.f, aB = 0.f;

#define LOADCH(P, ch)                                  \
    P##S0a = *(const float4*)&sD[ch][0][0];            \
    P##S0b = *(const float4*)&sD[ch][0][4];            \
    P##C1a = *(const float4*)&sD[ch][1][0];            \
    P##C1b = *(const float4*)&sD[ch][1][4];            \
    P##C2a = *(const float4*)&sD[ch][2][0];            \
    P##C2b = *(const float4*)&sD[ch][2][4];            \
    P##CRa = *(const float4*)&sD[ch][3][0];            \
    P##CRb = *(const float4*)&sD[ch][3][4];            \
    P##CGa = *(const float4*)&sD[ch][4][0];            \
    P##CGb = *(const float4*)&sD[ch][4][4];            \
    P##CBa = *(const float4*)&sD[ch][5][0];            \
    P##CBb = *(const float4*)&sD[ch][5][4];

#define ACC1(S0, C1, C2, CR, CG, CB)                                   \
    {                                                                  \
        const float e = bits2e(fmaf(t2, (C2), fmaf(t, (C1), (S0))));   \
        aR = fmaf(e, (CR), aR);                                        \
        aG = fmaf(e, (CG), aG);                                        \
        aB = fmaf(e, (CB), aB);                                        \
    }

#define ACC8(P)                                                        \
    ACC1(P##S0a.x, P##C1a.x, P##C2a.x, P##CRa.x, P##CGa.x, P##CBa.x)   \
    ACC1(P##S0a.y, P##C1a.y, P##C2a.y, P##CRa.y, P##CGa.y, P##CBa.y)   \
    ACC1(P##S0a.z, P##C1a.z, P##C2a.z, P##CRa.z, P##CGa.z, P##CBa.z)   \
    ACC1(P##S0a.w, P##C1a.w, P##C2a.w, P##CRa.w, P##CGa.w, P##CBa.w)   \
    ACC1(P##S0b.x, P##C1b.x, P##C2b.x, P##CRb.x, P##CGb.x, P##CBb.x)   \
    ACC1(P##S0b.y, P##C1b.y, P##C2b.y, P##CRb.y, P##CGb.y, P##CBb.y)   \
    ACC1(P##S0b.z, P##C1b.z, P##C2b.z, P##CRb.z, P##CGb.z, P##CBb.z)   \
    ACC1(P##S0b.w, P##C1b.w, P##C2b.w, P##CRb.w, P##CGb.w, P##CBb.w)

    float4 aS0a, aS0b, aC1a, aC1b, aC2a, aC2b, aCRa, aCRb, aCGa, aCGb, aCBa, aCBb;
    float4 bS0a, bS0b, bC1a, bC1b, bC2a, bC2b, bCRa, bCRb, bCGa, bCGb, bCBa, bCBb;

    LOADCH(a, 0)
    for (int ch = 0; ch < NCH; ch += 2) {
        LOADCH(b, ch + 1)          // prefetch BEFORE the exit check
        ACC8(a)
        if (__all(fminf(fminf(aR, aG), aB) > SAT_THR) || ch + 1 >= NCH) {
            break;
        }
        LOADCH(a, ch + 2)          // prefetch BEFORE the exit check
        ACC8(b)
        if (__all(fminf(fminf(aR, aG), aB) > SAT_THR)) {
            break;
        }
    }
#undef ACC8
#undef ACC1
#undef LOADCH

    const int idx = row * WW + tid;
    const int hw = HH * WW;
    out[0 * hw + idx] = clamp01(aR);
    out[1 * hw + idx] = clamp01(aG);
    out[2 * hw + idx] = clamp01(aB);
}

extern "C" void kernel_launch(void* const* d_in, const int* in_sizes, int n_in,
                              void* d_out, int out_size, void* d_ws, size_t ws_size,
                              hipStream_t stream) {
    const float* pos = (const float*)d_in[0];  // [1000,2]
    const float* sc  = (const float*)d_in[1];  // [1000,2]
    const float* rot = (const float*)d_in[2];  // [1000]
    const float* col = (const float*)d_in[3];  // [1000,3]
    const float* op  = (const float*)d_in[4];  // [1000]
    float* out = (float*)d_out;                // [3,512,512]

    gs_fused<<<HH, 512, 0, stream>>>(pos, sc, rot, col, op, out);
}